// Round 4
// baseline (658.256 us; speedup 1.0000x reference)
//
#include <hip/hip_runtime.h>

#define IN_SIZE 256
#define OUT_SIZE 64
#define N_NODES 512
#define FAN_IN 32
#define T_DIM 2048
#define D_DIM 832
#define TOTAL_EDGE 16384
#define BLK_F4 1088   // per-node block: 1024 f4 KV + 4 f4 meta + 60 f4 entries
#define MAX_ENT 60
#define THRESH -20.0f

// s_waitcnt: vmcnt<=N, don't wait lgkm/exp. gfx9 encoding:
// [3:0]=vm lo, [6:4]=exp, [11:8]=lgkm, [15:14]=vm hi.
#define WAITVM(N)                                                       \
  __builtin_amdgcn_s_waitcnt(((N) & 0xF) | (((N) >> 4) << 14) |         \
                             (0xF << 8) | (0x7 << 4))

typedef const __attribute__((address_space(1))) void gas_t;
typedef __attribute__((address_space(3))) void las_t;

__device__ __forceinline__ void lds_dma16(const float4* g, const float4* l,
                                          int lane) {
  __builtin_amdgcn_global_load_lds((gas_t*)(g + lane), (las_t*)l, 16, 0, 0);
}
__device__ __forceinline__ void issue_batch(const float4* gblk,
                                            const float4* lbuf, int lane) {
#pragma unroll
  for (int i = 0; i < 17; ++i) lds_dma16(gblk + i * 64, lbuf + i * 64, lane);
}

// DPP wave64 sum (lane 63 ends with total) — validated round 3
template <int CTRL, int RM>
__device__ __forceinline__ float dppadd(float v) {
  int m = __builtin_amdgcn_update_dpp(0, __float_as_int(v), CTRL, RM, 0xf, true);
  return v + __int_as_float(m);
}
__device__ __forceinline__ void wave_sum2(float& a, float& b) {
  a = dppadd<0x111, 0xf>(a); b = dppadd<0x111, 0xf>(b);
  a = dppadd<0x112, 0xf>(a); b = dppadd<0x112, 0xf>(b);
  a = dppadd<0x114, 0xf>(a); b = dppadd<0x114, 0xf>(b);
  a = dppadd<0x118, 0xf>(a); b = dppadd<0x118, 0xf>(b);
  a = dppadd<0x142, 0xa>(a); b = dppadd<0x142, 0xa>(b);
  a = dppadd<0x143, 0xc>(a); b = dppadd<0x143, 0xc>(b);
}
__device__ __forceinline__ float rl63(float v) {
  return __int_as_float(__builtin_amdgcn_readlane(__float_as_int(v), 63));
}

// ---------------------------------------------------------------------------
// Setup: inverted index (d>=2 edges) — hist, scan, fill. One block.
// ---------------------------------------------------------------------------
__global__ __launch_bounds__(1024) void setup_kernel(
    const int* __restrict__ in_idxs, const float* __restrict__ weights,
    int* __restrict__ offs_g, float4* __restrict__ entries_g) {
  __shared__ int scnt[N_NODES], sfill[N_NODES], soff[N_NODES + 1];
  __shared__ int wtot[8];
  int tid = threadIdx.x;
  if (tid < N_NODES) { scnt[tid] = 0; sfill[tid] = 0; }
  __syncthreads();
  for (int e = tid; e < TOTAL_EDGE; e += 1024) {
    int idx = in_idxs[e];
    int node = e >> 5;
    if (idx >= IN_SIZE && (idx - IN_SIZE) != node - 1)
      atomicAdd(&scnt[idx - IN_SIZE], 1);
  }
  __syncthreads();
  int incl = 0;
  if (tid < N_NODES) {
    incl = scnt[tid];
#pragma unroll
    for (int d = 1; d < 64; d <<= 1) {
      int u = __shfl_up(incl, d);
      if ((tid & 63) >= d) incl += u;
    }
    if ((tid & 63) == 63) wtot[tid >> 6] = incl;
  }
  __syncthreads();
  if (tid < N_NODES) {
    int add = 0;
    for (int w = 0; w < (tid >> 6); ++w) add += wtot[w];
    soff[tid + 1] = incl + add;
    if (tid == 0) soff[0] = 0;
  }
  __syncthreads();
  if (tid <= N_NODES) offs_g[tid] = soff[tid];
  for (int e = tid; e < TOTAL_EDGE; e += 1024) {
    int idx = in_idxs[e];
    int node = e >> 5;
    if (idx >= IN_SIZE && (idx - IN_SIZE) != node - 1) {
      int j = idx - IN_SIZE;
      int p = atomicAdd(&sfill[j], 1);
      const float* wp = weights + (size_t)e * 3;
      entries_g[soff[j] + p] =
          make_float4(__int_as_float(node), wp[0], wp[1], wp[2]);
    }
  }
}

// ---------------------------------------------------------------------------
// KV build (t-major, rows staged in LDS) — writes into blk KV area, t-order.
// Node stride = 2176 float2 (= BLK_F4 float4). Slot 2047 written zero.
// ---------------------------------------------------------------------------
__global__ __launch_bounds__(256) void kv_kernel(
    const float* __restrict__ actives, const int* __restrict__ in_idxs,
    const float* __restrict__ weights, float2* __restrict__ KVd) {
  __shared__ float rows[8][833];
  __shared__ int s_idx[64 * FAN_IN];
  __shared__ float2 s_w[64 * FAN_IN];
  int tid = threadIdx.x;
  int tb = blockIdx.x * 8;
  for (int i = tid; i < 8 * D_DIM; i += 256) {
    int r = i / D_DIM, c = i - r * D_DIM;
    int t = tb + r;
    rows[r][c] = (t < T_DIM - 1) ? actives[(size_t)(t + 1) * D_DIM + c] : 0.f;
  }
  int tl = tid & 7, ng = tid >> 3;
  for (int tile = 0; tile < 8; ++tile) {
    __syncthreads();
    int n0 = tile * 64;
    for (int i = tid; i < 64 * FAN_IN; i += 256) {
      int g = n0 * FAN_IN + i;
      s_idx[i] = in_idxs[g];
      const float* wp = weights + (size_t)g * 3;
      s_w[i] = make_float2(wp[1], wp[2]);
    }
    __syncthreads();
#pragma unroll
    for (int it = 0; it < 2; ++it) {
      int nl = ng + 32 * it;
      const int* ip = &s_idx[nl * FAN_IN];
      const float2* wp = &s_w[nl * FAN_IN];
      float k = 0.f, v = 0.f;
#pragma unroll 8
      for (int f = 0; f < FAN_IN; ++f) {
        float a = rows[tl][ip[f]];
        float2 w = wp[f];
        k = fmaf(w.x, a, k);
        v = fmaf(w.y, a, v);
      }
      KVd[(size_t)(n0 + nl) * (2 * BLK_F4) + tb + tl] = make_float2(k, v);
    }
  }
}

// ---------------------------------------------------------------------------
// Block build: per node — bucket KV ascending (64 bins), per-chunk k min/max,
// kmax/kmin, base dot from x, d1 patch weights, entry copy. Writes the
// 17408 B block consumed by seq.
// ---------------------------------------------------------------------------
__global__ __launch_bounds__(256) void block_kernel(
    const float* __restrict__ x, const int* __restrict__ in_idxs,
    const float* __restrict__ weights, const int* __restrict__ offs_g,
    const float4* __restrict__ entries_g, float4* __restrict__ blk,
    float4* __restrict__ Qb) {
  __shared__ float2 skv[T_DIM], sbk[T_DIM];
  __shared__ int hist[64];
  __shared__ float smx[4], smn[4];
  __shared__ float redn[4][4], redx[4][4];  // [wave][chunk]
  __shared__ float cfin[8];
  __shared__ float sadj[3];
  int node = blockIdx.x, tid = threadIdx.x;
  const float2* src = (const float2*)(blk + (size_t)node * BLK_F4);
  float mx = -3.4e38f, mn = 3.4e38f;
#pragma unroll
  for (int j = 0; j < 8; ++j) {
    int t = j * 256 + tid;
    float2 kv = (t < 2047) ? src[t] : make_float2(0.f, 0.f);
    skv[t] = kv;
    if (t < 2047) { mx = fmaxf(mx, kv.x); mn = fminf(mn, kv.x); }
  }
  if (tid < 64) hist[tid] = 0;
#pragma unroll
  for (int off = 32; off > 0; off >>= 1) {
    mx = fmaxf(mx, __shfl_xor(mx, off));
    mn = fminf(mn, __shfl_xor(mn, off));
  }
  if ((tid & 63) == 0) { smx[tid >> 6] = mx; smn[tid >> 6] = mn; }
  __syncthreads();
  float kmax = fmaxf(fmaxf(smx[0], smx[1]), fmaxf(smx[2], smx[3]));
  float kmin = fminf(fminf(smn[0], smn[1]), fminf(smn[2], smn[3]));
  float invbw = 64.0f / (kmax - kmin);
#pragma unroll
  for (int j = 0; j < 8; ++j) {
    int t = j * 256 + tid;
    if (t < 2047) {
      int b = (int)((skv[t].x - kmin) * invbw);
      b = b < 0 ? 0 : (b > 63 ? 63 : b);
      atomicAdd(&hist[b], 1);
    }
  }
  __syncthreads();
  if (tid < 64) {
    int v = hist[tid];
    int incl = v;
#pragma unroll
    for (int d = 1; d < 64; d <<= 1) {
      int u = __shfl_up(incl, d);
      if (tid >= d) incl += u;
    }
    hist[tid] = incl - v;  // exclusive prefix -> cursor
  }
  if (tid == 0) sbk[2047] = make_float2(0.f, 0.f);
  __syncthreads();
#pragma unroll
  for (int j = 0; j < 8; ++j) {
    int t = j * 256 + tid;
    if (t < 2047) {
      int b = (int)((skv[t].x - kmin) * invbw);
      b = b < 0 ? 0 : (b > 63 ? 63 : b);
      int p = atomicAdd(&hist[b], 1);
      sbk[p] = skv[t];
    }
  }
  __syncthreads();
  // per-chunk min/max (chunks of 512 slots; slot 2047 excluded)
  float cmn[4] = {3.4e38f, 3.4e38f, 3.4e38f, 3.4e38f};
  float cmx[4] = {-3.4e38f, -3.4e38f, -3.4e38f, -3.4e38f};
#pragma unroll
  for (int m = 0; m < 8; ++m) {
    int slot = tid + 256 * m;
    if (slot < 2047) {
      int c = slot >> 9;
      float k = sbk[slot].x;
      cmn[c] = fminf(cmn[c], k);
      cmx[c] = fmaxf(cmx[c], k);
    }
  }
#pragma unroll
  for (int c = 0; c < 4; ++c) {
#pragma unroll
    for (int off = 32; off > 0; off >>= 1) {
      cmn[c] = fminf(cmn[c], __shfl_xor(cmn[c], off));
      cmx[c] = fmaxf(cmx[c], __shfl_xor(cmx[c], off));
    }
  }
  if ((tid & 63) == 0) {
    int w = tid >> 6;
#pragma unroll
    for (int c = 0; c < 4; ++c) { redn[w][c] = cmn[c]; redx[w][c] = cmx[c]; }
  }
  // base dot + d1 patch (wave 0, lanes < 32)
  if (tid < 32) {
    int g = node * FAN_IN + tid;
    int idx = in_idxs[g];
    const float* wp = weights + (size_t)g * 3;
    float a = (idx < IN_SIZE) ? x[idx] : 0.f;
    bool d1 = (idx >= IN_SIZE) && (idx - IN_SIZE == node - 1);
    float p0 = a * wp[0], p1 = a * wp[1], p2 = a * wp[2];
    float p3 = d1 ? wp[0] : 0.f, p4 = d1 ? wp[1] : 0.f, p5 = d1 ? wp[2] : 0.f;
#pragma unroll
    for (int off = 16; off > 0; off >>= 1) {
      p0 += __shfl_xor(p0, off); p1 += __shfl_xor(p1, off);
      p2 += __shfl_xor(p2, off); p3 += __shfl_xor(p3, off);
      p4 += __shfl_xor(p4, off); p5 += __shfl_xor(p5, off);
    }
    if (tid == 0) {
      Qb[node] = make_float4(p0, p1, p2, 0.f);
      sadj[0] = p3; sadj[1] = p4; sadj[2] = p5;
    }
  }
  __syncthreads();
  if (tid == 0) {
#pragma unroll
    for (int c = 0; c < 4; ++c) {
      float a = fminf(fminf(redn[0][c], redn[1][c]),
                      fminf(redn[2][c], redn[3][c]));
      float b = fmaxf(fmaxf(redx[0][c], redx[1][c]),
                      fmaxf(redx[2][c], redx[3][c]));
      cfin[2 * c] = a;
      cfin[2 * c + 1] = b;
    }
  }
  __syncthreads();
  // write block
  float4* B = blk + (size_t)node * BLK_F4;
  for (int i = tid; i < 1024; i += 256) {
    float2 a = sbk[2 * i], b = sbk[2 * i + 1];
    B[i] = make_float4(a.x, a.y, b.x, b.y);
  }
  int off0 = offs_g[node], cnt = offs_g[node + 1] - off0;
  if (tid == 0) B[1024] = make_float4(kmax, kmin, __int_as_float(cnt), 0.f);
  if (tid == 1) B[1025] = make_float4(cfin[0], cfin[1], cfin[2], cfin[3]);
  if (tid == 2) B[1026] = make_float4(cfin[4], cfin[5], cfin[6], cfin[7]);
  if (tid == 3) B[1027] = make_float4(sadj[0], sadj[1], sadj[2], 0.f);
  if (tid < MAX_ENT)
    B[1028 + tid] = (tid < cnt) ? entries_g[off0 + tid]
                                : make_float4(0.f, 0.f, 0.f, 0.f);
}

// ---------------------------------------------------------------------------
// Sequential scan: 1 wave, zero barriers, explicit 3-deep LDS DMA pipeline.
// Per step: waitcnt vmcnt(17) -> compute node ix entirely from LDS/regs ->
// issue DMA for node ix+3 -> scatter -> rotate early-read state for ix+1.
// ---------------------------------------------------------------------------
__global__ __launch_bounds__(64) void seq_kernel(
    const float4* __restrict__ Qb, const int* __restrict__ offs_g,
    const float4* __restrict__ entries_g, const float4* __restrict__ blk,
    float* __restrict__ out) {
  __shared__ float4 sBuf[3][BLK_F4];   // 52224 B ring
  __shared__ float4 sQKV[N_NODES];     // pending (q,kl,vl) dots
  __shared__ int soffs[N_NODES + 1];
  __shared__ float souts[OUT_SIZE];
  const int lane = threadIdx.x;
  for (int i = lane; i < N_NODES; i += 64) sQKV[i] = Qb[i];
  for (int i = lane; i <= N_NODES; i += 64) soffs[i] = offs_g[i];

  // prime the pipeline: batches 0,1,2
  issue_batch(blk + 0 * BLK_F4, &sBuf[0][0], lane);
  issue_batch(blk + 1 * BLK_F4, &sBuf[1][0], lane);
  issue_batch(blk + 2 * BLK_F4, &sBuf[2][0], lane);
  WAITVM(34);  // batch 0 complete

  // pre-read node 0 state
  float4 meta = sBuf[0][1024];
  float4 cA = sBuf[0][1025];
  float4 cB = sBuf[0][1026];
  float4 adjn = sBuf[0][1027];  // unused for node 0 (no patch) — harmless
  float4 entc = (lane < MAX_ENT) ? sBuf[0][1028 + lane]
                                 : make_float4(0.f, 0.f, 0.f, 0.f);
  float4 fA[4], fB[4];
#pragma unroll
  for (int t = 0; t < 4; ++t) {
    fA[t] = sBuf[0][4 * lane + t];              // chunk 0
    fB[t] = sBuf[0][768 + 4 * lane + t];        // chunk 3
  }
  float4 qkv = sQKV[0];
  int bcur = 0;

  for (int ix = 0; ix < N_NODES; ++ix) {
    WAITVM(17);  // batches <= ix+1 complete
    int bnext = (bcur == 2) ? 0 : bcur + 1;
    int ixn = (ix + 1 < N_NODES) ? ix + 1 : N_NODES - 1;

    float q = qkv.x, kl = qkv.y, vl = qkv.z;
    float kmax = meta.x, kmin = meta.y;
    int cnt = __float_as_int(meta.z);
    float m = fmaxf(fmaxf(q * kmax, q * kmin), q * kl);
    float el = __expf(q * kl - m);
    bool asc = (q < 0.f);

    // chunk inclusion for the 3 non-first chunks in traversal order
    float b1 = asc ? q * cA.z : q * cB.y;   // asc: c1min | desc: c2max
    float b2 = asc ? q * cB.x : q * cA.w;   // asc: c2min | desc: c1max
    float b3 = asc ? q * cB.z : q * cA.y;   // asc: c3min | desc: c0max
    int c1i = asc ? 1 : 2, c2i = 2 - (asc ? 0 : 1), c3i = asc ? 3 : 0;
    bool p1 = (b1 - m) >= THRESH;
    bool p2 = p1 && ((b2 - m) >= THRESH);
    bool p3 = p2 && ((b3 - m) >= THRESH);

    // issue extra-chunk LDS reads (data resident: batch ix complete)
    const float4* bc = &sBuf[bcur][0];
    float4 x1[4], x2[4], x3[4];
    if (p1) {
      int base = c1i * 256 + 4 * lane;
#pragma unroll
      for (int t = 0; t < 4; ++t) x1[t] = bc[base + t];
    }
    if (p2) {
      int base = c2i * 256 + 4 * lane;
#pragma unroll
      for (int t = 0; t < 4; ++t) x2[t] = bc[base + t];
    }
    if (p3) {
      int base = c3i * 256 + 4 * lane;
#pragma unroll
      for (int t = 0; t < 4; ++t) x3[t] = bc[base + t];
    }

    // early reads for node ix+1 (batch ix+1 complete; sees scatters <= ix-1,
    // d1 term patched in registers below)
    const float4* bn = &sBuf[bnext][0];
    float4 metaN = bn[1024];
    float4 cAN = bn[1025];
    float4 cBN = bn[1026];
    float4 adjN = bn[1027];
    float4 entN = (lane < MAX_ENT) ? bn[1028 + lane]
                                   : make_float4(0.f, 0.f, 0.f, 0.f);
    float4 nfA[4], nfB[4];
#pragma unroll
    for (int t = 0; t < 4; ++t) {
      nfA[t] = bn[4 * lane + t];
      nfB[t] = bn[768 + 4 * lane + t];
    }
    float4 rawn = sQKV[ixn];

    // first chunk (regs): asc -> chunk 0, desc -> chunk 3 (mask slot 2047)
    float sw = 0.f, swv = 0.f;
#pragma unroll
    for (int t = 0; t < 4; ++t) {
      float4 e = make_float4(asc ? fA[t].x : fB[t].x, asc ? fA[t].y : fB[t].y,
                             asc ? fA[t].z : fB[t].z, asc ? fA[t].w : fB[t].w);
      float w0 = __expf(fmaf(q, e.x, -m));
      float w1 = __expf(fmaf(q, e.z, -m));
      if (t == 3 && !asc && lane == 63) w1 = 0.f;
      sw += w0 + w1;
      swv = fmaf(w0, e.y, fmaf(w1, e.w, swv));
    }
    if (p1) {
#pragma unroll
      for (int t = 0; t < 4; ++t) {
        float w0 = __expf(fmaf(q, x1[t].x, -m));
        float w1 = __expf(fmaf(q, x1[t].z, -m));
        sw += w0 + w1;
        swv = fmaf(w0, x1[t].y, fmaf(w1, x1[t].w, swv));
      }
    }
    if (p2) {
#pragma unroll
      for (int t = 0; t < 4; ++t) {
        float w0 = __expf(fmaf(q, x2[t].x, -m));
        float w1 = __expf(fmaf(q, x2[t].z, -m));
        sw += w0 + w1;
        swv = fmaf(w0, x2[t].y, fmaf(w1, x2[t].w, swv));
      }
    }
    if (p3) {
#pragma unroll
      for (int t = 0; t < 4; ++t) {
        float w0 = __expf(fmaf(q, x3[t].x, -m));
        float w1 = __expf(fmaf(q, x3[t].z, -m));
        if (t == 3 && asc && lane == 63) w1 = 0.f;  // slot 2047 in chunk 3
        sw += w0 + w1;
        swv = fmaf(w0, x3[t].y, fmaf(w1, x3[t].w, swv));
      }
    }

    // all reads of buffer bcur are consumed -> safe to refill it (node ix+3)
    int pf = (ix + 3 < N_NODES) ? ix + 3 : N_NODES - 1;
    issue_batch(blk + (size_t)pf * BLK_F4, &sBuf[bcur][0], lane);

    // reduce + finish
    wave_sum2(sw, swv);
    float S = rl63(sw) + el;
    float SV = fmaf(el, vl, rl63(swv));
    float z = SV * __builtin_amdgcn_rcpf(S);
    float eo = __expf(2.0f * z);
    float o = 1.0f - 2.0f * __builtin_amdgcn_rcpf(eo + 1.0f);
    if (lane == 0 && ix >= N_NODES - OUT_SIZE)
      souts[ix - (N_NODES - OUT_SIZE)] = o;

    // scatter o into pending dots (d>=2 consumers)
    int cblk = cnt < MAX_ENT ? cnt : MAX_ENT;
    if (lane < cblk) {
      int n = __float_as_int(entc.x);
      atomicAdd(&sQKV[n].x, o * entc.y);
      atomicAdd(&sQKV[n].y, o * entc.z);
      atomicAdd(&sQKV[n].z, o * entc.w);
    }
    for (int e2 = MAX_ENT + lane; e2 < cnt; e2 += 64) {  // ~never taken
      float4 ee = entries_g[soffs[ix] + e2];
      int n = __float_as_int(ee.x);
      atomicAdd(&sQKV[n].x, o * ee.y);
      atomicAdd(&sQKV[n].y, o * ee.z);
      atomicAdd(&sQKV[n].z, o * ee.w);
    }

    // rotate: d1 register patch completes node ix+1's pending dot
    qkv = make_float4(fmaf(o, adjN.x, rawn.x), fmaf(o, adjN.y, rawn.y),
                      fmaf(o, adjN.z, rawn.z), 0.f);
    meta = metaN; cA = cAN; cB = cBN; adjn = adjN; entc = entN;
#pragma unroll
    for (int t = 0; t < 4; ++t) { fA[t] = nfA[t]; fB[t] = nfB[t]; }
    bcur = bnext;
  }
  out[lane] = souts[lane];
}

// ---------------------------------------------------------------------------
extern "C" void kernel_launch(void* const* d_in, const int* in_sizes, int n_in,
                              void* d_out, int out_size, void* d_ws,
                              size_t ws_size, hipStream_t stream) {
  const float* x = (const float*)d_in[0];
  const float* actives = (const float*)d_in[1];
  const float* weights = (const float*)d_in[2];
  const int* in_idxs = (const int*)d_in[3];
  float* out = (float*)d_out;

  // workspace (~9.2 MB): blk | entries | Qb | offs
  char* ws = (char*)d_ws;
  float4* blk = (float4*)ws;                                   // 8,912,896 B
  size_t off = (size_t)N_NODES * BLK_F4 * 16;
  float4* entries = (float4*)(ws + off); off += (size_t)(TOTAL_EDGE + 64) * 16;
  float4* Qb = (float4*)(ws + off);      off += (size_t)N_NODES * 16;
  int* offs = (int*)(ws + off);

  setup_kernel<<<1, 1024, 0, stream>>>(in_idxs, weights, offs, entries);
  kv_kernel<<<T_DIM / 8, 256, 0, stream>>>(actives, in_idxs, weights,
                                           (float2*)blk);
  block_kernel<<<N_NODES, 256, 0, stream>>>(x, in_idxs, weights, offs, entries,
                                            blk, Qb);
  seq_kernel<<<1, 64, 0, stream>>>(Qb, offs, entries, blk, out);
}

// Round 5
// 606.094 us; speedup vs baseline: 1.0861x; 1.0861x over previous
//
#include <hip/hip_runtime.h>

#define IN_SIZE 256
#define OUT_SIZE 64
#define N_NODES 512
#define FAN_IN 32
#define T_DIM 2048
#define D_DIM 832
#define TOTAL_EDGE 16384
#define BLK_F4 1088   // 1024 f4 butterfly pairs + 3 f4 meta + 1 spare + 60 f4 entries
#define MAX_ENT 60
#define THRESH -20.0f
#define RING 4

// s_waitcnt: vmcnt<=N, don't wait lgkm/exp. gfx9 encoding:
// [3:0]=vm lo, [6:4]=exp, [11:8]=lgkm, [15:14]=vm hi.
#define WAITVM(N)                                                       \
  __builtin_amdgcn_s_waitcnt(((N) & 0xF) | (((N) >> 4) << 14) |         \
                             (0xF << 8) | (0x7 << 4))

typedef const __attribute__((address_space(1))) void gas_t;
typedef __attribute__((address_space(3))) void las_t;

__device__ __forceinline__ void lds_dma16(const float4* g, const float4* l,
                                          int lane) {
  __builtin_amdgcn_global_load_lds((gas_t*)(g + lane), (las_t*)l, 16, 0, 0);
}
__device__ __forceinline__ void issue_batch(const float4* gblk,
                                            const float4* lbuf, int lane) {
#pragma unroll
  for (int i = 0; i < 17; ++i) lds_dma16(gblk + i * 64, lbuf + i * 64, lane);
}

// DPP wave64 sum (lane 63 ends with total) — validated rounds 3/4
template <int CTRL, int RM>
__device__ __forceinline__ float dppadd(float v) {
  int m = __builtin_amdgcn_update_dpp(0, __float_as_int(v), CTRL, RM, 0xf, true);
  return v + __int_as_float(m);
}
__device__ __forceinline__ void wave_sum2(float& a, float& b) {
  a = dppadd<0x111, 0xf>(a); b = dppadd<0x111, 0xf>(b);
  a = dppadd<0x112, 0xf>(a); b = dppadd<0x112, 0xf>(b);
  a = dppadd<0x114, 0xf>(a); b = dppadd<0x114, 0xf>(b);
  a = dppadd<0x118, 0xf>(a); b = dppadd<0x118, 0xf>(b);
  a = dppadd<0x142, 0xa>(a); b = dppadd<0x142, 0xa>(b);
  a = dppadd<0x143, 0xc>(a); b = dppadd<0x143, 0xc>(b);
}
__device__ __forceinline__ float rl63(float v) {
  return __int_as_float(__builtin_amdgcn_readlane(__float_as_int(v), 63));
}

// ---------------------------------------------------------------------------
// Setup: inverted index (d>=2 edges) — hist, scan, fill. One block.
// ---------------------------------------------------------------------------
__global__ __launch_bounds__(1024) void setup_kernel(
    const int* __restrict__ in_idxs, const float* __restrict__ weights,
    int* __restrict__ offs_g, float4* __restrict__ entries_g) {
  __shared__ int scnt[N_NODES], sfill[N_NODES], soff[N_NODES + 1];
  __shared__ int wtot[8];
  int tid = threadIdx.x;
  if (tid < N_NODES) { scnt[tid] = 0; sfill[tid] = 0; }
  __syncthreads();
  for (int e = tid; e < TOTAL_EDGE; e += 1024) {
    int idx = in_idxs[e];
    int node = e >> 5;
    if (idx >= IN_SIZE && (idx - IN_SIZE) != node - 1)
      atomicAdd(&scnt[idx - IN_SIZE], 1);
  }
  __syncthreads();
  int incl = 0;
  if (tid < N_NODES) {
    incl = scnt[tid];
#pragma unroll
    for (int d = 1; d < 64; d <<= 1) {
      int u = __shfl_up(incl, d);
      if ((tid & 63) >= d) incl += u;
    }
    if ((tid & 63) == 63) wtot[tid >> 6] = incl;
  }
  __syncthreads();
  if (tid < N_NODES) {
    int add = 0;
    for (int w = 0; w < (tid >> 6); ++w) add += wtot[w];
    soff[tid + 1] = incl + add;
    if (tid == 0) soff[0] = 0;
  }
  __syncthreads();
  if (tid <= N_NODES) offs_g[tid] = soff[tid];
  for (int e = tid; e < TOTAL_EDGE; e += 1024) {
    int idx = in_idxs[e];
    int node = e >> 5;
    if (idx >= IN_SIZE && (idx - IN_SIZE) != node - 1) {
      int j = idx - IN_SIZE;
      int p = atomicAdd(&sfill[j], 1);
      const float* wp = weights + (size_t)e * 3;
      entries_g[soff[j] + p] =
          make_float4(__int_as_float(node), wp[0], wp[1], wp[2]);
    }
  }
}

// ---------------------------------------------------------------------------
// KV build (t-major, rows staged in LDS) — writes into blk KV area, t-order.
// Node stride = 2176 float2 (= BLK_F4 float4). Slot 2047 written zero.
// ---------------------------------------------------------------------------
__global__ __launch_bounds__(256) void kv_kernel(
    const float* __restrict__ actives, const int* __restrict__ in_idxs,
    const float* __restrict__ weights, float2* __restrict__ KVd) {
  __shared__ float rows[8][833];
  __shared__ int s_idx[64 * FAN_IN];
  __shared__ float2 s_w[64 * FAN_IN];
  int tid = threadIdx.x;
  int tb = blockIdx.x * 8;
  for (int i = tid; i < 8 * D_DIM; i += 256) {
    int r = i / D_DIM, c = i - r * D_DIM;
    int t = tb + r;
    rows[r][c] = (t < T_DIM - 1) ? actives[(size_t)(t + 1) * D_DIM + c] : 0.f;
  }
  int tl = tid & 7, ng = tid >> 3;
  for (int tile = 0; tile < 8; ++tile) {
    __syncthreads();
    int n0 = tile * 64;
    for (int i = tid; i < 64 * FAN_IN; i += 256) {
      int g = n0 * FAN_IN + i;
      s_idx[i] = in_idxs[g];
      const float* wp = weights + (size_t)g * 3;
      s_w[i] = make_float2(wp[1], wp[2]);
    }
    __syncthreads();
#pragma unroll
    for (int it = 0; it < 2; ++it) {
      int nl = ng + 32 * it;
      const int* ip = &s_idx[nl * FAN_IN];
      const float2* wp = &s_w[nl * FAN_IN];
      float k = 0.f, v = 0.f;
#pragma unroll 8
      for (int f = 0; f < FAN_IN; ++f) {
        float a = rows[tl][ip[f]];
        float2 w = wp[f];
        k = fmaf(w.x, a, k);
        v = fmaf(w.y, a, v);
      }
      KVd[(size_t)(n0 + nl) * (2 * BLK_F4) + tb + tl] = make_float2(k, v);
    }
  }
}

// ---------------------------------------------------------------------------
// Block build: bucket-sort k ascending, emit BUTTERFLY pairs
// B[p] = (asc_k, asc_v, desc_k, desc_v), p in [0,1024); pair 1023's desc side
// duplicates the median (masked in seq). Meta: kmax/kmin/cnt + prefix-skip
// boundary k's + d1 patch weights. Plus base dot from x and entry copy.
// ---------------------------------------------------------------------------
__global__ __launch_bounds__(256) void block_kernel(
    const float* __restrict__ x, const int* __restrict__ in_idxs,
    const float* __restrict__ weights, const int* __restrict__ offs_g,
    const float4* __restrict__ entries_g, float4* __restrict__ blk,
    float4* __restrict__ Qb) {
  __shared__ float2 skv[T_DIM], sbk[T_DIM];
  __shared__ int hist[64];
  __shared__ float smx[4], smn[4];
  __shared__ float sadj[3];
  int node = blockIdx.x, tid = threadIdx.x;
  const float2* src = (const float2*)(blk + (size_t)node * BLK_F4);
  float mx = -3.4e38f, mn = 3.4e38f;
#pragma unroll
  for (int j = 0; j < 8; ++j) {
    int t = j * 256 + tid;
    float2 kv = (t < 2047) ? src[t] : make_float2(0.f, 0.f);
    skv[t] = kv;
    if (t < 2047) { mx = fmaxf(mx, kv.x); mn = fminf(mn, kv.x); }
  }
  if (tid < 64) hist[tid] = 0;
#pragma unroll
  for (int off = 32; off > 0; off >>= 1) {
    mx = fmaxf(mx, __shfl_xor(mx, off));
    mn = fminf(mn, __shfl_xor(mn, off));
  }
  if ((tid & 63) == 0) { smx[tid >> 6] = mx; smn[tid >> 6] = mn; }
  __syncthreads();
  float kmax = fmaxf(fmaxf(smx[0], smx[1]), fmaxf(smx[2], smx[3]));
  float kmin = fminf(fminf(smn[0], smn[1]), fminf(smn[2], smn[3]));
  float invbw = 64.0f / (kmax - kmin);
#pragma unroll
  for (int j = 0; j < 8; ++j) {
    int t = j * 256 + tid;
    if (t < 2047) {
      int b = (int)((skv[t].x - kmin) * invbw);
      b = b < 0 ? 0 : (b > 63 ? 63 : b);
      atomicAdd(&hist[b], 1);
    }
  }
  __syncthreads();
  if (tid < 64) {
    int v = hist[tid];
    int incl = v;
#pragma unroll
    for (int d = 1; d < 64; d <<= 1) {
      int u = __shfl_up(incl, d);
      if (tid >= d) incl += u;
    }
    hist[tid] = incl - v;  // exclusive prefix -> cursor
  }
  if (tid == 0) sbk[2047] = make_float2(0.f, 0.f);
  __syncthreads();
#pragma unroll
  for (int j = 0; j < 8; ++j) {
    int t = j * 256 + tid;
    if (t < 2047) {
      int b = (int)((skv[t].x - kmin) * invbw);
      b = b < 0 ? 0 : (b > 63 ? 63 : b);
      int p = atomicAdd(&hist[b], 1);
      sbk[p] = skv[t];
    }
  }
  // base dot + d1 patch weights (wave 0, lanes < 32)
  if (tid < 32) {
    int g = node * FAN_IN + tid;
    int idx = in_idxs[g];
    const float* wp = weights + (size_t)g * 3;
    float a = (idx < IN_SIZE) ? x[idx] : 0.f;
    bool d1 = (idx >= IN_SIZE) && (idx - IN_SIZE == node - 1);
    float p0 = a * wp[0], p1 = a * wp[1], p2 = a * wp[2];
    float p3 = d1 ? wp[0] : 0.f, p4 = d1 ? wp[1] : 0.f, p5 = d1 ? wp[2] : 0.f;
#pragma unroll
    for (int off = 16; off > 0; off >>= 1) {
      p0 += __shfl_xor(p0, off); p1 += __shfl_xor(p1, off);
      p2 += __shfl_xor(p2, off); p3 += __shfl_xor(p3, off);
      p4 += __shfl_xor(p4, off); p5 += __shfl_xor(p5, off);
    }
    if (tid == 0) {
      Qb[node] = make_float4(p0, p1, p2, 0.f);
      sadj[0] = p3; sadj[1] = p4; sadj[2] = p5;
    }
  }
  __syncthreads();  // sbk scatter + sadj complete
  float4* B = blk + (size_t)node * BLK_F4;
  for (int i = tid; i < 1024; i += 256) {
    float2 a = sbk[i];
    float2 d = sbk[2046 - i];
    B[i] = make_float4(a.x, a.y, d.x, d.y);
  }
  int off0 = offs_g[node], cnt = offs_g[node + 1] - off0;
  if (tid == 0)
    B[1024] = make_float4(kmax, kmin, __int_as_float(cnt), sbk[256].x);
  if (tid == 1)
    B[1025] = make_float4(sbk[1790].x, sbk[512].x, sbk[1534].x, sbk[768].x);
  if (tid == 2)
    B[1026] = make_float4(sbk[1278].x, sadj[0], sadj[1], sadj[2]);
  if (tid == 3) B[1027] = make_float4(0.f, 0.f, 0.f, 0.f);
  if (tid < MAX_ENT)
    B[1028 + tid] = (tid < cnt) ? entries_g[off0 + tid]
                                : make_float4(0.f, 0.f, 0.f, 0.f);
}

// ---------------------------------------------------------------------------
// Sequential scan: 1 wave, zero barriers, 4-deep LDS DMA ring (3-step lead).
// Butterfly pairs: prefix blocks of 256 pairs cover both k-extremes; skip
// predicates from meta alone. All per-lane LDS reads are 16 B contiguous
// (conflict-free). WAITVM(34) gates batch ix+1 complete.
// ---------------------------------------------------------------------------
__global__ __launch_bounds__(64) void seq_kernel(
    const float4* __restrict__ Qb, const int* __restrict__ offs_g,
    const float4* __restrict__ entries_g, const float4* __restrict__ blk,
    float* __restrict__ out) {
  __shared__ float4 sBuf[RING][BLK_F4];  // 69632 B ring
  __shared__ float4 sQKV[N_NODES];       // pending (q,kl,vl) dots
  __shared__ int soffs[N_NODES + 1];
  __shared__ float souts[OUT_SIZE];
  const int lane = threadIdx.x;
  for (int i = lane; i < N_NODES; i += 64) sQKV[i] = Qb[i];
  for (int i = lane; i <= N_NODES; i += 64) soffs[i] = offs_g[i];

  issue_batch(blk + 0 * BLK_F4, &sBuf[0][0], lane);
  issue_batch(blk + 1 * BLK_F4, &sBuf[1][0], lane);
  issue_batch(blk + 2 * BLK_F4, &sBuf[2][0], lane);
  issue_batch(blk + 3 * BLK_F4, &sBuf[3][0], lane);
  WAITVM(51);  // batch 0 complete

  // pre-read node 0 state (all reads 16 B/lane contiguous)
  const float4* b0 = &sBuf[0][0];
  float4 meta0 = b0[1024], meta1 = b0[1025], meta2 = b0[1026];
  float4 entc = (lane < MAX_ENT) ? b0[1028 + lane]
                                 : make_float4(0.f, 0.f, 0.f, 0.f);
  float4 f0[4];
#pragma unroll
  for (int t = 0; t < 4; ++t) f0[t] = b0[64 * t + lane];
  float4 qkv = sQKV[0];
  int bcur = 0;

  for (int ix = 0; ix < N_NODES; ++ix) {
    WAITVM(34);  // batches <= ix+1 complete (2 outstanding)
    int bnext = (bcur + 1) & (RING - 1);
    int ixn = (ix + 1 < N_NODES) ? ix + 1 : N_NODES - 1;
    const float4* bc = &sBuf[bcur][0];
    const float4* bn = &sBuf[bnext][0];

    float q = qkv.x, kl = qkv.y, vl = qkv.z;
    int cnt = __float_as_int(meta0.z);
    float m = fmaxf(fmaxf(q * meta0.x, q * meta0.y), q * kl);
    float el = __expf(q * kl - m);
    // prefix-skip predicates (wave-uniform, from meta only)
    bool p1 = fmaxf(q * meta0.w, q * meta1.x) - m >= THRESH;
    bool p2 = p1 && (fmaxf(q * meta1.y, q * meta1.z) - m >= THRESH);
    bool p3 = p2 && (fmaxf(q * meta1.w, q * meta2.x) - m >= THRESH);

    // issue conditional pair-block reads (conflict-free: base + lane)
    float4 x1[4], x2[4], x3[4];
    if (p1) {
#pragma unroll
      for (int t = 0; t < 4; ++t) x1[t] = bc[256 + 64 * t + lane];
    }
    if (p2) {
#pragma unroll
      for (int t = 0; t < 4; ++t) x2[t] = bc[512 + 64 * t + lane];
    }
    if (p3) {
#pragma unroll
      for (int t = 0; t < 4; ++t) x3[t] = bc[768 + 64 * t + lane];
    }
    // early reads for node ix+1 (batch ix+1 complete)
    float4 meta0N = bn[1024], meta1N = bn[1025], meta2N = bn[1026];
    float4 entN = (lane < MAX_ENT) ? bn[1028 + lane]
                                   : make_float4(0.f, 0.f, 0.f, 0.f);
    float4 nf0[4];
#pragma unroll
    for (int t = 0; t < 4; ++t) nf0[t] = bn[64 * t + lane];
    float4 rawn = sQKV[ixn];

    // pair-block 0 (from regs): wrong-direction side underflows to exp=0
    float sw = 0.f, swv = 0.f;
#pragma unroll
    for (int t = 0; t < 4; ++t) {
      float w0 = __expf(fmaf(q, f0[t].x, -m));
      float w1 = __expf(fmaf(q, f0[t].z, -m));
      sw += w0 + w1;
      swv = fmaf(w0, f0[t].y, fmaf(w1, f0[t].w, swv));
    }
    if (p1) {
#pragma unroll
      for (int t = 0; t < 4; ++t) {
        float w0 = __expf(fmaf(q, x1[t].x, -m));
        float w1 = __expf(fmaf(q, x1[t].z, -m));
        sw += w0 + w1;
        swv = fmaf(w0, x1[t].y, fmaf(w1, x1[t].w, swv));
      }
    }
    if (p2) {
#pragma unroll
      for (int t = 0; t < 4; ++t) {
        float w0 = __expf(fmaf(q, x2[t].x, -m));
        float w1 = __expf(fmaf(q, x2[t].z, -m));
        sw += w0 + w1;
        swv = fmaf(w0, x2[t].y, fmaf(w1, x2[t].w, swv));
      }
    }
    if (p3) {
#pragma unroll
      for (int t = 0; t < 4; ++t) {
        float w0 = __expf(fmaf(q, x3[t].x, -m));
        float w1 = __expf(fmaf(q, x3[t].z, -m));
        if (t == 3 && lane == 63) w1 = 0.f;  // pair 1023 desc = median dup
        sw += w0 + w1;
        swv = fmaf(w0, x3[t].y, fmaf(w1, x3[t].w, swv));
      }
    }

    // all reads of bcur consumed -> refill with batch ix+RING
    int pf = (ix + RING < N_NODES) ? ix + RING : N_NODES - 1;
    issue_batch(blk + (size_t)pf * BLK_F4, &sBuf[bcur][0], lane);

    // reduce + finish
    wave_sum2(sw, swv);
    float S = rl63(sw) + el;
    float SV = fmaf(el, vl, rl63(swv));
    float z = SV * __builtin_amdgcn_rcpf(S);
    float eo = __expf(2.0f * z);
    float o = 1.0f - 2.0f * __builtin_amdgcn_rcpf(eo + 1.0f);
    if (lane == 0 && ix >= N_NODES - OUT_SIZE)
      souts[ix - (N_NODES - OUT_SIZE)] = o;

    // scatter o into pending dots (d>=2 consumers; never targets ix+1)
    int cblk = cnt < MAX_ENT ? cnt : MAX_ENT;
    if (lane < cblk) {
      int n = __float_as_int(entc.x);
      atomicAdd(&sQKV[n].x, o * entc.y);
      atomicAdd(&sQKV[n].y, o * entc.z);
      atomicAdd(&sQKV[n].z, o * entc.w);
    }
    for (int e2 = MAX_ENT + lane; e2 < cnt; e2 += 64) {  // ~never taken
      float4 ee = entries_g[soffs[ix] + e2];
      int n = __float_as_int(ee.x);
      atomicAdd(&sQKV[n].x, o * ee.y);
      atomicAdd(&sQKV[n].y, o * ee.z);
      atomicAdd(&sQKV[n].z, o * ee.w);
    }

    // rotate: d1 register patch (adj in meta2N.yzw) completes node ix+1's dot
    qkv = make_float4(fmaf(o, meta2N.y, rawn.x), fmaf(o, meta2N.z, rawn.y),
                      fmaf(o, meta2N.w, rawn.z), 0.f);
    meta0 = meta0N; meta1 = meta1N; meta2 = meta2N; entc = entN;
#pragma unroll
    for (int t = 0; t < 4; ++t) f0[t] = nf0[t];
    bcur = bnext;
  }
  out[lane] = souts[lane];
}

// ---------------------------------------------------------------------------
extern "C" void kernel_launch(void* const* d_in, const int* in_sizes, int n_in,
                              void* d_out, int out_size, void* d_ws,
                              size_t ws_size, hipStream_t stream) {
  const float* x = (const float*)d_in[0];
  const float* actives = (const float*)d_in[1];
  const float* weights = (const float*)d_in[2];
  const int* in_idxs = (const int*)d_in[3];
  float* out = (float*)d_out;

  // workspace (~9.2 MB): blk | entries | Qb | offs
  char* ws = (char*)d_ws;
  float4* blk = (float4*)ws;  // 8,912,896 B
  size_t off = (size_t)N_NODES * BLK_F4 * 16;
  float4* entries = (float4*)(ws + off); off += (size_t)(TOTAL_EDGE + 64) * 16;
  float4* Qb = (float4*)(ws + off);      off += (size_t)N_NODES * 16;
  int* offs = (int*)(ws + off);

  setup_kernel<<<1, 1024, 0, stream>>>(in_idxs, weights, offs, entries);
  kv_kernel<<<T_DIM / 8, 256, 0, stream>>>(actives, in_idxs, weights,
                                           (float2*)blk);
  block_kernel<<<N_NODES, 256, 0, stream>>>(x, in_idxs, weights, offs, entries,
                                            blk, Qb);
  seq_kernel<<<1, 64, 0, stream>>>(Qb, offs, entries, blk, out);
}

// Round 6
// 430.926 us; speedup vs baseline: 1.5275x; 1.4065x over previous
//
#include <hip/hip_runtime.h>

#define IN_SIZE 256
#define OUT_SIZE 64
#define N_NODES 512
#define FAN_IN 32
#define T_DIM 2048
#define D_DIM 832
#define TOTAL_EDGE 16384
#define BLK_F4 1088   // 1024 f4 butterfly pairs + 3 f4 meta + 1 spare + 60 f4 entries
#define MAX_ENT 60
#define THRESH -20.0f

// DPP wave64 sum (lane 63 ends with total) — validated rounds 3/4/5
template <int CTRL, int RM>
__device__ __forceinline__ float dppadd(float v) {
  int m = __builtin_amdgcn_update_dpp(0, __float_as_int(v), CTRL, RM, 0xf, true);
  return v + __int_as_float(m);
}
__device__ __forceinline__ void wave_sum2(float& a, float& b) {
  a = dppadd<0x111, 0xf>(a); b = dppadd<0x111, 0xf>(b);
  a = dppadd<0x112, 0xf>(a); b = dppadd<0x112, 0xf>(b);
  a = dppadd<0x114, 0xf>(a); b = dppadd<0x114, 0xf>(b);
  a = dppadd<0x118, 0xf>(a); b = dppadd<0x118, 0xf>(b);
  a = dppadd<0x142, 0xa>(a); b = dppadd<0x142, 0xa>(b);
  a = dppadd<0x143, 0xc>(a); b = dppadd<0x143, 0xc>(b);
}
__device__ __forceinline__ float rl63(float v) {
  return __int_as_float(__builtin_amdgcn_readlane(__float_as_int(v), 63));
}

// ---------------------------------------------------------------------------
// Setup: inverted index (d>=2 edges) — hist, scan, fill. One block.
// (identical to round 5)
// ---------------------------------------------------------------------------
__global__ __launch_bounds__(1024) void setup_kernel(
    const int* __restrict__ in_idxs, const float* __restrict__ weights,
    int* __restrict__ offs_g, float4* __restrict__ entries_g) {
  __shared__ int scnt[N_NODES], sfill[N_NODES], soff[N_NODES + 1];
  __shared__ int wtot[8];
  int tid = threadIdx.x;
  if (tid < N_NODES) { scnt[tid] = 0; sfill[tid] = 0; }
  __syncthreads();
  for (int e = tid; e < TOTAL_EDGE; e += 1024) {
    int idx = in_idxs[e];
    int node = e >> 5;
    if (idx >= IN_SIZE && (idx - IN_SIZE) != node - 1)
      atomicAdd(&scnt[idx - IN_SIZE], 1);
  }
  __syncthreads();
  int incl = 0;
  if (tid < N_NODES) {
    incl = scnt[tid];
#pragma unroll
    for (int d = 1; d < 64; d <<= 1) {
      int u = __shfl_up(incl, d);
      if ((tid & 63) >= d) incl += u;
    }
    if ((tid & 63) == 63) wtot[tid >> 6] = incl;
  }
  __syncthreads();
  if (tid < N_NODES) {
    int add = 0;
    for (int w = 0; w < (tid >> 6); ++w) add += wtot[w];
    soff[tid + 1] = incl + add;
    if (tid == 0) soff[0] = 0;
  }
  __syncthreads();
  if (tid <= N_NODES) offs_g[tid] = soff[tid];
  for (int e = tid; e < TOTAL_EDGE; e += 1024) {
    int idx = in_idxs[e];
    int node = e >> 5;
    if (idx >= IN_SIZE && (idx - IN_SIZE) != node - 1) {
      int j = idx - IN_SIZE;
      int p = atomicAdd(&sfill[j], 1);
      const float* wp = weights + (size_t)e * 3;
      entries_g[soff[j] + p] =
          make_float4(__int_as_float(node), wp[0], wp[1], wp[2]);
    }
  }
}

// ---------------------------------------------------------------------------
// KV build (t-major, rows staged in LDS) — identical to round 5.
// ---------------------------------------------------------------------------
__global__ __launch_bounds__(256) void kv_kernel(
    const float* __restrict__ actives, const int* __restrict__ in_idxs,
    const float* __restrict__ weights, float2* __restrict__ KVd) {
  __shared__ float rows[8][833];
  __shared__ int s_idx[64 * FAN_IN];
  __shared__ float2 s_w[64 * FAN_IN];
  int tid = threadIdx.x;
  int tb = blockIdx.x * 8;
  for (int i = tid; i < 8 * D_DIM; i += 256) {
    int r = i / D_DIM, c = i - r * D_DIM;
    int t = tb + r;
    rows[r][c] = (t < T_DIM - 1) ? actives[(size_t)(t + 1) * D_DIM + c] : 0.f;
  }
  int tl = tid & 7, ng = tid >> 3;
  for (int tile = 0; tile < 8; ++tile) {
    __syncthreads();
    int n0 = tile * 64;
    for (int i = tid; i < 64 * FAN_IN; i += 256) {
      int g = n0 * FAN_IN + i;
      s_idx[i] = in_idxs[g];
      const float* wp = weights + (size_t)g * 3;
      s_w[i] = make_float2(wp[1], wp[2]);
    }
    __syncthreads();
#pragma unroll
    for (int it = 0; it < 2; ++it) {
      int nl = ng + 32 * it;
      const int* ip = &s_idx[nl * FAN_IN];
      const float2* wp = &s_w[nl * FAN_IN];
      float k = 0.f, v = 0.f;
#pragma unroll 8
      for (int f = 0; f < FAN_IN; ++f) {
        float a = rows[tl][ip[f]];
        float2 w = wp[f];
        k = fmaf(w.x, a, k);
        v = fmaf(w.y, a, v);
      }
      KVd[(size_t)(n0 + nl) * (2 * BLK_F4) + tb + tl] = make_float2(k, v);
    }
  }
}

// ---------------------------------------------------------------------------
// Block build: butterfly pairs + meta + entries — identical to round 5.
// ---------------------------------------------------------------------------
__global__ __launch_bounds__(256) void block_kernel(
    const float* __restrict__ x, const int* __restrict__ in_idxs,
    const float* __restrict__ weights, const int* __restrict__ offs_g,
    const float4* __restrict__ entries_g, float4* __restrict__ blk,
    float4* __restrict__ Qb) {
  __shared__ float2 skv[T_DIM], sbk[T_DIM];
  __shared__ int hist[64];
  __shared__ float smx[4], smn[4];
  __shared__ float sadj[3];
  int node = blockIdx.x, tid = threadIdx.x;
  const float2* src = (const float2*)(blk + (size_t)node * BLK_F4);
  float mx = -3.4e38f, mn = 3.4e38f;
#pragma unroll
  for (int j = 0; j < 8; ++j) {
    int t = j * 256 + tid;
    float2 kv = (t < 2047) ? src[t] : make_float2(0.f, 0.f);
    skv[t] = kv;
    if (t < 2047) { mx = fmaxf(mx, kv.x); mn = fminf(mn, kv.x); }
  }
  if (tid < 64) hist[tid] = 0;
#pragma unroll
  for (int off = 32; off > 0; off >>= 1) {
    mx = fmaxf(mx, __shfl_xor(mx, off));
    mn = fminf(mn, __shfl_xor(mn, off));
  }
  if ((tid & 63) == 0) { smx[tid >> 6] = mx; smn[tid >> 6] = mn; }
  __syncthreads();
  float kmax = fmaxf(fmaxf(smx[0], smx[1]), fmaxf(smx[2], smx[3]));
  float kmin = fminf(fminf(smn[0], smn[1]), fminf(smn[2], smn[3]));
  float invbw = 64.0f / (kmax - kmin);
#pragma unroll
  for (int j = 0; j < 8; ++j) {
    int t = j * 256 + tid;
    if (t < 2047) {
      int b = (int)((skv[t].x - kmin) * invbw);
      b = b < 0 ? 0 : (b > 63 ? 63 : b);
      atomicAdd(&hist[b], 1);
    }
  }
  __syncthreads();
  if (tid < 64) {
    int v = hist[tid];
    int incl = v;
#pragma unroll
    for (int d = 1; d < 64; d <<= 1) {
      int u = __shfl_up(incl, d);
      if (tid >= d) incl += u;
    }
    hist[tid] = incl - v;  // exclusive prefix -> cursor
  }
  if (tid == 0) sbk[2047] = make_float2(0.f, 0.f);
  __syncthreads();
#pragma unroll
  for (int j = 0; j < 8; ++j) {
    int t = j * 256 + tid;
    if (t < 2047) {
      int b = (int)((skv[t].x - kmin) * invbw);
      b = b < 0 ? 0 : (b > 63 ? 63 : b);
      int p = atomicAdd(&hist[b], 1);
      sbk[p] = skv[t];
    }
  }
  // base dot + d1 patch weights (wave 0, lanes < 32)
  if (tid < 32) {
    int g = node * FAN_IN + tid;
    int idx = in_idxs[g];
    const float* wp = weights + (size_t)g * 3;
    float a = (idx < IN_SIZE) ? x[idx] : 0.f;
    bool d1 = (idx >= IN_SIZE) && (idx - IN_SIZE == node - 1);
    float p0 = a * wp[0], p1 = a * wp[1], p2 = a * wp[2];
    float p3 = d1 ? wp[0] : 0.f, p4 = d1 ? wp[1] : 0.f, p5 = d1 ? wp[2] : 0.f;
#pragma unroll
    for (int off = 16; off > 0; off >>= 1) {
      p0 += __shfl_xor(p0, off); p1 += __shfl_xor(p1, off);
      p2 += __shfl_xor(p2, off); p3 += __shfl_xor(p3, off);
      p4 += __shfl_xor(p4, off); p5 += __shfl_xor(p5, off);
    }
    if (tid == 0) {
      Qb[node] = make_float4(p0, p1, p2, 0.f);
      sadj[0] = p3; sadj[1] = p4; sadj[2] = p5;
    }
  }
  __syncthreads();  // sbk scatter + sadj complete
  float4* B = blk + (size_t)node * BLK_F4;
  for (int i = tid; i < 1024; i += 256) {
    float2 a = sbk[i];
    float2 d = sbk[2046 - i];
    B[i] = make_float4(a.x, a.y, d.x, d.y);
  }
  int off0 = offs_g[node], cnt = offs_g[node + 1] - off0;
  if (tid == 0)
    B[1024] = make_float4(kmax, kmin, __int_as_float(cnt), sbk[256].x);
  if (tid == 1)
    B[1025] = make_float4(sbk[1790].x, sbk[512].x, sbk[1534].x, sbk[768].x);
  if (tid == 2)
    B[1026] = make_float4(sbk[1278].x, sadj[0], sadj[1], sadj[2]);
  if (tid == 3) B[1027] = make_float4(0.f, 0.f, 0.f, 0.f);
  if (tid < MAX_ENT)
    B[1028 + tid] = (tid < cnt) ? entries_g[off0 + tid]
                                : make_float4(0.f, 0.f, 0.f, 0.f);
}

// ---------------------------------------------------------------------------
// Sequential scan: 1 wave, zero barriers, NO global_load_lds. All per-node
// data flows through VGPRs with 2-step-lead plain loads (compiler-precise
// vmcnt). Meta in a one-shot LDS table; pending dots in LDS (in-order DS).
// ---------------------------------------------------------------------------
__global__ __launch_bounds__(64) void seq_kernel(
    const float4* __restrict__ Qb, const int* __restrict__ offs_g,
    const float4* __restrict__ entries_g, const float4* __restrict__ blk,
    float* __restrict__ out) {
  __shared__ float4 sMeta[N_NODES][3];  // 24 KB: kmax/kmin/cnt/bounds/adj
  __shared__ float4 sQKV[N_NODES];      // pending (q,kl,vl) dots
  __shared__ int soffs[N_NODES + 1];
  const int lane = threadIdx.x;
  const int elane = (lane < MAX_ENT) ? lane : 0;
  for (int n = lane; n < N_NODES; n += 64) {
    const float4* B = blk + (size_t)n * BLK_F4;
    sMeta[n][0] = B[1024];
    sMeta[n][1] = B[1025];
    sMeta[n][2] = B[1026];
    sQKV[n] = Qb[n];
  }
  for (int i = lane; i <= N_NODES; i += 64) soffs[i] = offs_g[i];
  // single wave: per-wave in-order DS ops, no barrier needed anywhere

  // register pipeline: sets A (even nodes) / B (odd nodes), depth 2
  float4 f0A[4], f0B[4], tlA[12], tlB[12], entA, entB;
  {
    const float4* B0 = blk;
    const float4* B1 = blk + BLK_F4;
#pragma unroll
    for (int t = 0; t < 4; ++t) {
      f0A[t] = B0[64 * t + lane];
      f0B[t] = B1[64 * t + lane];
    }
#pragma unroll
    for (int t = 0; t < 12; ++t) {
      tlA[t] = B0[256 + 64 * t + lane];
      tlB[t] = B1[256 + 64 * t + lane];
    }
    entA = B0[1028 + elane];
    entB = B1[1028 + elane];
  }
  float4 qkv = Qb[0];  // node 0 has no d1 predecessor -> exact
  float4 mC0 = sMeta[0][0], mC1 = sMeta[0][1], mC2 = sMeta[0][2];

  auto step = [&](int ix, float4(&F0)[4], float4(&TL)[12], float4& ENT) {
    int ixn = (ix + 1 < N_NODES) ? ix + 1 : N_NODES - 1;
    int ix2 = (ix + 2 < N_NODES) ? ix + 2 : N_NODES - 1;
    // early broadcast LDS reads for node ix+1 (sees scatters <= ix-1; the
    // d1 term is patched in registers at rotate)
    float4 rawn = sQKV[ixn];
    float4 mN0 = sMeta[ixn][0], mN1 = sMeta[ixn][1], mN2 = sMeta[ixn][2];

    float q = qkv.x, kl = qkv.y, vl = qkv.z;
    int cnt = __float_as_int(mC0.z);
    float m = fmaxf(fmaxf(q * mC0.x, q * mC0.y), q * kl);
    float el = __expf(q * kl - m);
    // exact prefix-skip predicates (gate COMPUTE only; data already loaded)
    bool p1 = fmaxf(q * mC0.w, q * mC1.x) - m >= THRESH;
    bool p2 = p1 && (fmaxf(q * mC1.y, q * mC1.z) - m >= THRESH);
    bool p3 = p2 && (fmaxf(q * mC1.w, q * mC2.x) - m >= THRESH);

    // pair-block 0 (always): wrong-direction side underflows to exp(=0)
    float sw = 0.f, swv = 0.f;
#pragma unroll
    for (int t = 0; t < 4; ++t) {
      float w0 = __expf(fmaf(q, F0[t].x, -m));
      float w1 = __expf(fmaf(q, F0[t].z, -m));
      sw += w0 + w1;
      swv = fmaf(w0, F0[t].y, fmaf(w1, F0[t].w, swv));
    }
    if (p1) {
#pragma unroll
      for (int t = 0; t < 4; ++t) {
        float w0 = __expf(fmaf(q, TL[t].x, -m));
        float w1 = __expf(fmaf(q, TL[t].z, -m));
        sw += w0 + w1;
        swv = fmaf(w0, TL[t].y, fmaf(w1, TL[t].w, swv));
      }
    }
    if (p2) {
#pragma unroll
      for (int t = 4; t < 8; ++t) {
        float w0 = __expf(fmaf(q, TL[t].x, -m));
        float w1 = __expf(fmaf(q, TL[t].z, -m));
        sw += w0 + w1;
        swv = fmaf(w0, TL[t].y, fmaf(w1, TL[t].w, swv));
      }
    }
    if (p3) {
#pragma unroll
      for (int t = 8; t < 12; ++t) {
        float w0 = __expf(fmaf(q, TL[t].x, -m));
        float w1 = __expf(fmaf(q, TL[t].z, -m));
        if (t == 11 && lane == 63) w1 = 0.f;  // pair 1023 desc = median dup
        sw += w0 + w1;
        swv = fmaf(w0, TL[t].y, fmaf(w1, TL[t].w, swv));
      }
    }

    // F0/TL consumed -> refill with node ix+2 (plain loads, ~2-step lead,
    // compiler emits precise per-register vmcnt)
    const float4* Bn = blk + (size_t)ix2 * BLK_F4;
#pragma unroll
    for (int t = 0; t < 4; ++t) F0[t] = Bn[64 * t + lane];
#pragma unroll
    for (int t = 0; t < 12; ++t) TL[t] = Bn[256 + 64 * t + lane];

    // reduce + finish
    wave_sum2(sw, swv);
    float S = rl63(sw) + el;
    float SV = fmaf(el, vl, rl63(swv));
    float z = SV * __builtin_amdgcn_rcpf(S);
    float eo = __expf(2.f * z);
    float o = 1.f - 2.f * __builtin_amdgcn_rcpf(eo + 1.f);
    if (lane == 0 && ix >= N_NODES - OUT_SIZE)
      out[ix - (N_NODES - OUT_SIZE)] = o;

    // scatter o into pending dots (d>=2 consumers; never targets ix+1)
    int cblk = cnt < MAX_ENT ? cnt : MAX_ENT;
    if (lane < cblk) {
      int n = __float_as_int(ENT.x);
      atomicAdd(&sQKV[n].x, o * ENT.y);
      atomicAdd(&sQKV[n].y, o * ENT.z);
      atomicAdd(&sQKV[n].z, o * ENT.w);
    }
    for (int e2 = MAX_ENT + lane; e2 < cnt; e2 += 64) {  // ~never taken
      float4 ee = entries_g[soffs[ix] + e2];
      int n = __float_as_int(ee.x);
      atomicAdd(&sQKV[n].x, o * ee.y);
      atomicAdd(&sQKV[n].y, o * ee.z);
      atomicAdd(&sQKV[n].z, o * ee.w);
    }
    ENT = Bn[1028 + elane];  // refill after use

    // rotate: d1 register patch (adj = mN2.yzw) completes node ix+1's dot
    qkv = make_float4(fmaf(o, mN2.y, rawn.x), fmaf(o, mN2.z, rawn.y),
                      fmaf(o, mN2.w, rawn.z), 0.f);
    mC0 = mN0; mC1 = mN1; mC2 = mN2;
  };

  for (int ix = 0; ix < N_NODES; ix += 2) {
    step(ix, f0A, tlA, entA);
    step(ix + 1, f0B, tlB, entB);
  }
}

// ---------------------------------------------------------------------------
extern "C" void kernel_launch(void* const* d_in, const int* in_sizes, int n_in,
                              void* d_out, int out_size, void* d_ws,
                              size_t ws_size, hipStream_t stream) {
  const float* x = (const float*)d_in[0];
  const float* actives = (const float*)d_in[1];
  const float* weights = (const float*)d_in[2];
  const int* in_idxs = (const int*)d_in[3];
  float* out = (float*)d_out;

  // workspace (~9.2 MB): blk | entries | Qb | offs
  char* ws = (char*)d_ws;
  float4* blk = (float4*)ws;  // 8,912,896 B
  size_t off = (size_t)N_NODES * BLK_F4 * 16;
  float4* entries = (float4*)(ws + off); off += (size_t)(TOTAL_EDGE + 64) * 16;
  float4* Qb = (float4*)(ws + off);      off += (size_t)N_NODES * 16;
  int* offs = (int*)(ws + off);

  setup_kernel<<<1, 1024, 0, stream>>>(in_idxs, weights, offs, entries);
  kv_kernel<<<T_DIM / 8, 256, 0, stream>>>(actives, in_idxs, weights,
                                           (float2*)blk);
  block_kernel<<<N_NODES, 256, 0, stream>>>(x, in_idxs, weights, offs, entries,
                                            blk, Qb);
  seq_kernel<<<1, 64, 0, stream>>>(Qb, offs, entries, blk, out);
}

// Round 7
// 422.351 us; speedup vs baseline: 1.5586x; 1.0203x over previous
//
#include <hip/hip_runtime.h>

#define IN_SIZE 256
#define OUT_SIZE 64
#define N_NODES 512
#define FAN_IN 32
#define T_DIM 2048
#define D_DIM 832
#define TOTAL_EDGE 16384
#define BLK_F4 1092   // 1024 f4 butterfly pairs + 4 f4 meta + 64 f4 entries
#define MAX_ENT 64
#define THRESH -20.0f

// DPP wave64 sum (lane 63 ends with total) — validated rounds 3..6
template <int CTRL, int RM>
__device__ __forceinline__ float dppadd(float v) {
  int m = __builtin_amdgcn_update_dpp(0, __float_as_int(v), CTRL, RM, 0xf, true);
  return v + __int_as_float(m);
}
__device__ __forceinline__ void wave_sum2(float& a, float& b) {
  a = dppadd<0x111, 0xf>(a); b = dppadd<0x111, 0xf>(b);
  a = dppadd<0x112, 0xf>(a); b = dppadd<0x112, 0xf>(b);
  a = dppadd<0x114, 0xf>(a); b = dppadd<0x114, 0xf>(b);
  a = dppadd<0x118, 0xf>(a); b = dppadd<0x118, 0xf>(b);
  a = dppadd<0x142, 0xa>(a); b = dppadd<0x142, 0xa>(b);
  a = dppadd<0x143, 0xc>(a); b = dppadd<0x143, 0xc>(b);
}
__device__ __forceinline__ float rl63(float v) {
  return __int_as_float(__builtin_amdgcn_readlane(__float_as_int(v), 63));
}

// ---------------------------------------------------------------------------
// KV build (t-major, rows staged in LDS). Writes (k,v) in t-order into each
// node's block KV area. Slot 2047 written zero.
// ---------------------------------------------------------------------------
__global__ __launch_bounds__(256) void kv_kernel(
    const float* __restrict__ actives, const int* __restrict__ in_idxs,
    const float* __restrict__ weights, float2* __restrict__ KVd) {
  __shared__ float rows[8][833];
  __shared__ int s_idx[64 * FAN_IN];
  __shared__ float2 s_w[64 * FAN_IN];
  int tid = threadIdx.x;
  int tb = blockIdx.x * 8;
  for (int i = tid; i < 8 * D_DIM; i += 256) {
    int r = i / D_DIM, c = i - r * D_DIM;
    int t = tb + r;
    rows[r][c] = (t < T_DIM - 1) ? actives[(size_t)(t + 1) * D_DIM + c] : 0.f;
  }
  int tl = tid & 7, ng = tid >> 3;
  for (int tile = 0; tile < 8; ++tile) {
    __syncthreads();
    int n0 = tile * 64;
    for (int i = tid; i < 64 * FAN_IN; i += 256) {
      int g = n0 * FAN_IN + i;
      s_idx[i] = in_idxs[g];
      const float* wp = weights + (size_t)g * 3;
      s_w[i] = make_float2(wp[1], wp[2]);
    }
    __syncthreads();
#pragma unroll
    for (int it = 0; it < 2; ++it) {
      int nl = ng + 32 * it;
      const int* ip = &s_idx[nl * FAN_IN];
      const float2* wp = &s_w[nl * FAN_IN];
      float k = 0.f, v = 0.f;
#pragma unroll 8
      for (int f = 0; f < FAN_IN; ++f) {
        float a = rows[tl][ip[f]];
        float2 w = wp[f];
        k = fmaf(w.x, a, k);
        v = fmaf(w.y, a, v);
      }
      KVd[(size_t)(n0 + nl) * (2 * BLK_F4) + tb + tl] = make_float2(k, v);
    }
  }
}

// ---------------------------------------------------------------------------
// Block build: bucket-sort k ascending -> butterfly pairs
// B[p] = (asc_k, asc_v, desc_k, desc_v); meta (kmax/kmin/cnt/skip-bounds/adj);
// base dot from x; SELF-BUILT consumer entry list (scans all in_idxs, no
// global CSR / setup kernel needed; entries for this node's output, d>=2).
// ---------------------------------------------------------------------------
__global__ __launch_bounds__(256) void block_kernel(
    const float* __restrict__ x, const int* __restrict__ in_idxs,
    const float* __restrict__ weights, float4* __restrict__ blk,
    float4* __restrict__ Qb) {
  __shared__ float2 skv[T_DIM], sbk[T_DIM];
  __shared__ int hist[64];
  __shared__ float smx[4], smn[4];
  __shared__ float sadj[3];
  __shared__ float4 sEnt[MAX_ENT];
  __shared__ int ecnt;
  int node = blockIdx.x, tid = threadIdx.x;
  if (tid == 0) ecnt = 0;
  const float2* src = (const float2*)(blk + (size_t)node * BLK_F4);
  float mx = -3.4e38f, mn = 3.4e38f;
#pragma unroll
  for (int j = 0; j < 8; ++j) {
    int t = j * 256 + tid;
    float2 kv = (t < 2047) ? src[t] : make_float2(0.f, 0.f);
    skv[t] = kv;
    if (t < 2047) { mx = fmaxf(mx, kv.x); mn = fminf(mn, kv.x); }
  }
  if (tid < 64) hist[tid] = 0;
#pragma unroll
  for (int off = 32; off > 0; off >>= 1) {
    mx = fmaxf(mx, __shfl_xor(mx, off));
    mn = fminf(mn, __shfl_xor(mn, off));
  }
  if ((tid & 63) == 0) { smx[tid >> 6] = mx; smn[tid >> 6] = mn; }
  __syncthreads();
  float kmax = fmaxf(fmaxf(smx[0], smx[1]), fmaxf(smx[2], smx[3]));
  float kmin = fminf(fminf(smn[0], smn[1]), fminf(smn[2], smn[3]));
  float invbw = 64.0f / (kmax - kmin);
#pragma unroll
  for (int j = 0; j < 8; ++j) {
    int t = j * 256 + tid;
    if (t < 2047) {
      int b = (int)((skv[t].x - kmin) * invbw);
      b = b < 0 ? 0 : (b > 63 ? 63 : b);
      atomicAdd(&hist[b], 1);
    }
  }
  // consumer entry scan: edges e with in_idxs[e] == 256+node, consumer != node+1
  {
    int target = IN_SIZE + node;
    for (int e = tid; e < TOTAL_EDGE; e += 256) {
      if (in_idxs[e] == target) {
        int c = e >> 5;
        if (c != node + 1) {
          int p = atomicAdd(&ecnt, 1);
          if (p < MAX_ENT) {
            const float* wp = weights + (size_t)e * 3;
            sEnt[p] = make_float4(__int_as_float(c), wp[0], wp[1], wp[2]);
          }
        }
      }
    }
  }
  __syncthreads();
  if (tid < 64) {
    int v = hist[tid];
    int incl = v;
#pragma unroll
    for (int d = 1; d < 64; d <<= 1) {
      int u = __shfl_up(incl, d);
      if (tid >= d) incl += u;
    }
    hist[tid] = incl - v;  // exclusive prefix -> cursor
  }
  if (tid == 0) sbk[2047] = make_float2(0.f, 0.f);
  __syncthreads();
#pragma unroll
  for (int j = 0; j < 8; ++j) {
    int t = j * 256 + tid;
    if (t < 2047) {
      int b = (int)((skv[t].x - kmin) * invbw);
      b = b < 0 ? 0 : (b > 63 ? 63 : b);
      int p = atomicAdd(&hist[b], 1);
      sbk[p] = skv[t];
    }
  }
  // base dot + d1 patch weights (wave 0, lanes < 32)
  if (tid < 32) {
    int g = node * FAN_IN + tid;
    int idx = in_idxs[g];
    const float* wp = weights + (size_t)g * 3;
    float a = (idx < IN_SIZE) ? x[idx] : 0.f;
    bool d1 = (idx >= IN_SIZE) && (idx - IN_SIZE == node - 1);
    float p0 = a * wp[0], p1 = a * wp[1], p2 = a * wp[2];
    float p3 = d1 ? wp[0] : 0.f, p4 = d1 ? wp[1] : 0.f, p5 = d1 ? wp[2] : 0.f;
#pragma unroll
    for (int off = 16; off > 0; off >>= 1) {
      p0 += __shfl_xor(p0, off); p1 += __shfl_xor(p1, off);
      p2 += __shfl_xor(p2, off); p3 += __shfl_xor(p3, off);
      p4 += __shfl_xor(p4, off); p5 += __shfl_xor(p5, off);
    }
    if (tid == 0) {
      Qb[node] = make_float4(p0, p1, p2, 0.f);
      sadj[0] = p3; sadj[1] = p4; sadj[2] = p5;
    }
  }
  __syncthreads();  // sbk scatter + sadj + sEnt complete
  float4* B = blk + (size_t)node * BLK_F4;
  for (int i = tid; i < 1024; i += 256) {
    float2 a = sbk[i];
    float2 d = sbk[2046 - i];
    B[i] = make_float4(a.x, a.y, d.x, d.y);
  }
  int cnt = ecnt < MAX_ENT ? ecnt : MAX_ENT;
  if (tid == 0)
    B[1024] = make_float4(kmax, kmin, __int_as_float(cnt), sbk[256].x);
  if (tid == 1)
    B[1025] = make_float4(sbk[1790].x, sbk[512].x, sbk[1534].x, sbk[768].x);
  if (tid == 2)
    B[1026] = make_float4(sbk[1278].x, sadj[0], sadj[1], sadj[2]);
  if (tid == 3) B[1027] = make_float4(0.f, 0.f, 0.f, 0.f);
  if (tid < MAX_ENT)
    B[1028 + tid] = (tid < cnt) ? sEnt[tid] : make_float4(0.f, 0.f, 0.f, 0.f);
}

// ---------------------------------------------------------------------------
// Sequential scan: 1 wave, zero barriers, plain VGPR loads with 2-step lead.
// __launch_bounds__(64, 1) unlocks the full 512-VGPR budget so the A/B
// pipeline (f0 + 12-f4 tails + entries, x2 sets = ~200 VGPRs) stays
// register-resident (r6's compiler capped at 132 and sank the loads).
// ---------------------------------------------------------------------------
__global__ __launch_bounds__(64, 1) void seq_kernel(
    const float4* __restrict__ Qb, const float4* __restrict__ blk,
    float* __restrict__ out) {
  __shared__ float4 sMeta[N_NODES][3];  // 24 KB meta table
  __shared__ float4 sQKV[N_NODES];      // pending (q,kl,vl) dots
  __shared__ float souts[OUT_SIZE];
  const int lane = threadIdx.x;
  for (int n = lane; n < N_NODES; n += 64) {
    const float4* B = blk + (size_t)n * BLK_F4;
    sMeta[n][0] = B[1024];
    sMeta[n][1] = B[1025];
    sMeta[n][2] = B[1026];
    sQKV[n] = Qb[n];
  }
  // single wave: per-wave in-order DS ops, no barrier needed anywhere

  float4 f0A[4], f0B[4], tlA[12], tlB[12], entA, entB;
  {
    const float4* B0 = blk;
    const float4* B1 = blk + BLK_F4;
#pragma unroll
    for (int t = 0; t < 4; ++t) {
      f0A[t] = B0[64 * t + lane];
      f0B[t] = B1[64 * t + lane];
    }
#pragma unroll
    for (int t = 0; t < 12; ++t) {
      tlA[t] = B0[256 + 64 * t + lane];
      tlB[t] = B1[256 + 64 * t + lane];
    }
    entA = B0[1028 + lane];
    entB = B1[1028 + lane];
  }
  float4 qkv = Qb[0];  // node 0 has no d1 predecessor -> exact
  float4 mC0 = sMeta[0][0], mC1 = sMeta[0][1], mC2 = sMeta[0][2];

  auto step = [&](int ix, float4(&F0)[4], float4(&TL)[12], float4& ENT) {
    int ixn = (ix + 1 < N_NODES) ? ix + 1 : N_NODES - 1;
    int ix2 = (ix + 2 < N_NODES) ? ix + 2 : N_NODES - 1;
    // early broadcast LDS reads for node ix+1 (sees scatters <= ix-1; the
    // d1 term is patched in registers at rotate)
    float4 rawn = sQKV[ixn];
    float4 mN0 = sMeta[ixn][0], mN1 = sMeta[ixn][1], mN2 = sMeta[ixn][2];

    float q = qkv.x, kl = qkv.y, vl = qkv.z;
    int cnt = __float_as_int(mC0.z);
    float m = fmaxf(fmaxf(q * mC0.x, q * mC0.y), q * kl);
    float el = __expf(q * kl - m);
    // exact prefix-skip predicates (gate COMPUTE only; data already loaded)
    bool p1 = fmaxf(q * mC0.w, q * mC1.x) - m >= THRESH;
    bool p2 = p1 && (fmaxf(q * mC1.y, q * mC1.z) - m >= THRESH);
    bool p3 = p2 && (fmaxf(q * mC1.w, q * mC2.x) - m >= THRESH);

    // pair-block 0 (always): wrong-direction side underflows to exp(=0).
    // dual accumulators shorten the serial add chain.
    float swa = 0.f, swb = 0.f, sva = 0.f, svb = 0.f;
#pragma unroll
    for (int t = 0; t < 4; ++t) {
      float w0 = __expf(fmaf(q, F0[t].x, -m));
      float w1 = __expf(fmaf(q, F0[t].z, -m));
      if (t & 1) {
        swb += w0 + w1;
        svb = fmaf(w0, F0[t].y, fmaf(w1, F0[t].w, svb));
      } else {
        swa += w0 + w1;
        sva = fmaf(w0, F0[t].y, fmaf(w1, F0[t].w, sva));
      }
    }
    if (p1) {
#pragma unroll
      for (int t = 0; t < 4; ++t) {
        float w0 = __expf(fmaf(q, TL[t].x, -m));
        float w1 = __expf(fmaf(q, TL[t].z, -m));
        if (t & 1) {
          swb += w0 + w1;
          svb = fmaf(w0, TL[t].y, fmaf(w1, TL[t].w, svb));
        } else {
          swa += w0 + w1;
          sva = fmaf(w0, TL[t].y, fmaf(w1, TL[t].w, sva));
        }
      }
    }
    if (p2) {
#pragma unroll
      for (int t = 4; t < 8; ++t) {
        float w0 = __expf(fmaf(q, TL[t].x, -m));
        float w1 = __expf(fmaf(q, TL[t].z, -m));
        if (t & 1) {
          swb += w0 + w1;
          svb = fmaf(w0, TL[t].y, fmaf(w1, TL[t].w, svb));
        } else {
          swa += w0 + w1;
          sva = fmaf(w0, TL[t].y, fmaf(w1, TL[t].w, sva));
        }
      }
    }
    if (p3) {
#pragma unroll
      for (int t = 8; t < 12; ++t) {
        float w0 = __expf(fmaf(q, TL[t].x, -m));
        float w1 = __expf(fmaf(q, TL[t].z, -m));
        if (t == 11 && lane == 63) w1 = 0.f;  // pair 1023 desc = median dup
        if (t & 1) {
          swb += w0 + w1;
          svb = fmaf(w0, TL[t].y, fmaf(w1, TL[t].w, svb));
        } else {
          swa += w0 + w1;
          sva = fmaf(w0, TL[t].y, fmaf(w1, TL[t].w, sva));
        }
      }
    }

    // F0/TL consumed -> refill with node ix+2 (2-step lead, register-resident)
    const float4* Bn = blk + (size_t)ix2 * BLK_F4;
#pragma unroll
    for (int t = 0; t < 4; ++t) F0[t] = Bn[64 * t + lane];
#pragma unroll
    for (int t = 0; t < 12; ++t) TL[t] = Bn[256 + 64 * t + lane];

    // reduce + finish
    float sw = swa + swb, swv = sva + svb;
    wave_sum2(sw, swv);
    float S = rl63(sw) + el;
    float SV = fmaf(el, vl, rl63(swv));
    float z = SV * __builtin_amdgcn_rcpf(S);
    float eo = __expf(2.f * z);
    float o = 1.f - 2.f * __builtin_amdgcn_rcpf(eo + 1.f);
    if (lane == 0 && ix >= N_NODES - OUT_SIZE)
      souts[ix - (N_NODES - OUT_SIZE)] = o;  // LDS-buffered, flushed at end

    // scatter o into pending dots (d>=2 consumers; never targets ix+1)
    if (lane < cnt) {
      int n = __float_as_int(ENT.x);
      atomicAdd(&sQKV[n].x, o * ENT.y);
      atomicAdd(&sQKV[n].y, o * ENT.z);
      atomicAdd(&sQKV[n].z, o * ENT.w);
    }
    ENT = Bn[1028 + lane];  // refill after use

    // rotate: d1 register patch (adj = mN2.yzw) completes node ix+1's dot
    qkv = make_float4(fmaf(o, mN2.y, rawn.x), fmaf(o, mN2.z, rawn.y),
                      fmaf(o, mN2.w, rawn.z), 0.f);
    mC0 = mN0; mC1 = mN1; mC2 = mN2;
  };

  for (int ix = 0; ix < N_NODES; ix += 2) {
    step(ix, f0A, tlA, entA);
    step(ix + 1, f0B, tlB, entB);
  }
  out[lane] = souts[lane];
}

// ---------------------------------------------------------------------------
extern "C" void kernel_launch(void* const* d_in, const int* in_sizes, int n_in,
                              void* d_out, int out_size, void* d_ws,
                              size_t ws_size, hipStream_t stream) {
  const float* x = (const float*)d_in[0];
  const float* actives = (const float*)d_in[1];
  const float* weights = (const float*)d_in[2];
  const int* in_idxs = (const int*)d_in[3];
  float* out = (float*)d_out;

  // workspace (~9.0 MB): blk | Qb
  char* ws = (char*)d_ws;
  float4* blk = (float4*)ws;  // 512 * 1092 * 16 = 8,945,664 B
  float4* Qb = (float4*)(ws + (size_t)N_NODES * BLK_F4 * 16);

  kv_kernel<<<T_DIM / 8, 256, 0, stream>>>(actives, in_idxs, weights,
                                           (float2*)blk);
  block_kernel<<<N_NODES, 256, 0, stream>>>(x, in_idxs, weights, blk, Qb);
  seq_kernel<<<1, 64, 0, stream>>>(Qb, blk, out);
}